// Round 9
// baseline (467.287 us; speedup 1.0000x reference)
//
#include <hip/hip_runtime.h>
#include <hip/hip_bf16.h>

#define NN 100000
#define EE 1250000

#define RL(x, l) __builtin_amdgcn_readlane((x), (l))
#define RLF(x, l) __int_as_float(__builtin_amdgcn_readlane(__float_as_int(x), (l)))

typedef __attribute__((ext_vector_type(8))) short v8s;
typedef __attribute__((ext_vector_type(4))) float v4f;
typedef __attribute__((ext_vector_type(4))) unsigned int v4u;

__device__ __forceinline__ unsigned short bf16rtn(float x) {
    unsigned u = __float_as_uint(x);
    unsigned r = u + 0x7fffu + ((u >> 16) & 1u);
    return (unsigned short)(r >> 16);
}
__device__ __forceinline__ unsigned bf16rtn2(float lo, float hi) {
    return (unsigned)bf16rtn(lo) | ((unsigned)bf16rtn(hi) << 16);
}
__device__ __forceinline__ float bflo(unsigned u) { return __uint_as_float(u << 16); }
__device__ __forceinline__ float bfhi(unsigned u) { return __uint_as_float(u & 0xffff0000u); }
__device__ __forceinline__ float bfs(unsigned short s) { return __uint_as_float((unsigned)s << 16); }

// ---------------- CSR build (packed; R9-proven) ----------------
// Atomic pass: ~23 G TRANSACTIONS/s memory-side atomic ceiling (R2..R10).
// R18 lesson: atomics are TCC/memory-side on this chip — even non-returning
// fp32 atomicAdd costs a full fabric transaction + 64B write-through
// (k_fill +52us). zacc folding REVERTED.
// R15 (kept): k_deg folded into k_count's 64-bit packed atomic.

__global__ __launch_bounds__(256) void k_count(const int* __restrict__ ei,
                                               const float* __restrict__ ew,
                                               unsigned long long* __restrict__ cnt,
                                               int* __restrict__ slot) {
    int e = blockIdx.x * 256 + threadIdx.x;
    if (e >= EE) return;
    int d = __builtin_nontemporal_load(&ei[EE + e]);
    float w = __builtin_nontemporal_load(&ew[e]);
    unsigned fx = (unsigned)(w * 16777216.0f + 0.5f);   // w in [0,1] -> <= 2^24
    unsigned long long old =
        atomicAdd(&cnt[d], (1ULL << 32) | (unsigned long long)fx);
    __builtin_nontemporal_store((int)(old >> 32), &slot[e]);
}

__global__ __launch_bounds__(256) void k_bsum(const unsigned long long* __restrict__ cnt,
                                              int* __restrict__ bsum) {
    __shared__ int ls[256];
    int b = blockIdx.x, tid = threadIdx.x;
    int base = b * 1024 + tid * 4;
    int s = 0;
    #pragma unroll
    for (int j = 0; j < 4; ++j) { int g = base + j; if (g < NN) s += (int)(cnt[g] >> 32); }
    ls[tid] = s; __syncthreads();
    for (int off = 128; off > 0; off >>= 1) {
        if (tid < off) ls[tid] += ls[tid + off];
        __syncthreads();
    }
    if (tid == 0) bsum[b] = ls[0];
}

__global__ __launch_bounds__(256) void k_scan_out(const unsigned long long* __restrict__ cnt,
                                                  const int* __restrict__ bsum,
                                                  const float* __restrict__ x,
                                                  int* __restrict__ rowptr,
                                                  float* __restrict__ dinv,
                                                  float* __restrict__ xd) {
    __shared__ int ls[256];
    __shared__ int sbase;
    int b = blockIdx.x, tid = threadIdx.x;
    if (tid < 64) {
        int w0 = (tid < b) ? bsum[tid] : 0;
        int w1 = ((64 + tid) < b) ? bsum[64 + tid] : 0;
        int s = w0 + w1;
        #pragma unroll
        for (int m = 32; m >= 1; m >>= 1) s += __shfl_xor(s, m, 64);
        if (tid == 0) sbase = s;
    }
    int base = b * 1024 + tid * 4;
    int c[4]; float sw[4]; int s = 0;
    #pragma unroll
    for (int j = 0; j < 4; ++j) {
        int g = base + j;
        unsigned long long v = (g < NN) ? cnt[g] : 0ULL;
        c[j] = (int)(v >> 32);
        sw[j] = (float)(unsigned)(v & 0xffffffffu) * (1.0f / 16777216.0f);
        s += c[j];
    }
    ls[tid] = s; __syncthreads();
    for (int off = 1; off < 256; off <<= 1) {
        int v = (tid >= off) ? ls[tid - off] : 0;
        __syncthreads();
        ls[tid] += v;
        __syncthreads();
    }
    int excl = ls[tid] - s + sbase;
    #pragma unroll
    for (int j = 0; j < 4; ++j) {
        int g = base + j;
        if (g < NN) {
            rowptr[g + 1] = excl + c[j];
            excl += c[j];
            float di = rsqrtf(sw[j] + 1.0f);
            dinv[g] = di;
            xd[g] = di * x[g];
        }
    }
    if (b == 0 && tid == 0) rowptr[0] = 0;
}

__global__ __launch_bounds__(256) void k_fill(const int* __restrict__ ei,
                                              const float* __restrict__ ew,
                                              const int* __restrict__ slot,
                                              const int* __restrict__ rowptr,
                                              int2* __restrict__ epair) {
    int e = blockIdx.x * 256 + threadIdx.x;
    if (e >= EE) return;
    int s = __builtin_nontemporal_load(&ei[e]);
    int d = __builtin_nontemporal_load(&ei[EE + e]);
    float w = __builtin_nontemporal_load(&ew[e]);
    int sl = __builtin_nontemporal_load(&slot[e]);
    int p = rowptr[d] + sl;
    epair[p] = make_int2(s, __float_as_int(w));
}

// ---------------- W pre-pack for MFMA (R12, R13-fixed) ----------------
// Packs 64x64 fp32 W into mfma_f32_16x16x32_bf16 B-fragment order, SPLIT
// hi+lo bf16 (fp32-equivalent W). 16 KB per W. R13: 512 slots (i<2).
// grid = 4 blocks: {W3, W4, W5, fW1}.
__global__ __launch_bounds__(256) void k_wpk(const float* __restrict__ Wa,
                                             const float* __restrict__ Wb,
                                             const float* __restrict__ Wc,
                                             const float* __restrict__ Wd,
                                             unsigned* __restrict__ Wf) {
    const float* W = (blockIdx.x == 0) ? Wa : (blockIdx.x == 1) ? Wb
                   : (blockIdx.x == 2) ? Wc : Wd;
    unsigned* out = Wf + blockIdx.x * 4096;
    int t = threadIdx.x;
    #pragma unroll
    for (int i = 0; i < 2; ++i) {
        int s = t * 2 + i;
        int lane = s & 63;
        int nt = (s >> 6) & 3;
        int kt = s >> 8;                 // 0..1
        int col = nt * 16 + (lane & 15);
        int k0 = kt * 32 + (lane >> 4) * 8;
        unsigned hi[4], lo[4];
        #pragma unroll
        for (int d = 0; d < 4; ++d) {
            float w0 = W[(k0 + 2 * d) * 64 + col];
            float w1 = W[(k0 + 2 * d + 1) * 64 + col];
            unsigned short h0 = bf16rtn(w0), h1 = bf16rtn(w1);
            float r0 = w0 - bfs(h0), r1 = w1 - bfs(h1);
            hi[d] = (unsigned)h0 | ((unsigned)h1 << 16);
            lo[d] = (unsigned)bf16rtn(r0) | ((unsigned)bf16rtn(r1) << 16);
        }
        int gh = (0 * 2 + kt) * 4 + nt;
        int gl = (1 * 2 + kt) * 4 + nt;
        *(v4u*)&out[(gh * 64 + lane) * 4] = (v4u){hi[0], hi[1], hi[2], hi[3]};
        *(v4u*)&out[(gl * 64 + lane) * 4] = (v4u){lo[0], lo[1], lo[2], lo[3]};
    }
}

// ---------------- Layers ----------------
// Identity: Agg_l[d] = dinv_d * ( G'_l[d] + sum_e w_e * G'_l[src] ).
// R19: G' and v stored QUARTER-MAJOR bf16 — quarter q (16 features, 32 B)
// of all nodes is a contiguous 3.2 MB region that fits ONE XCD's 4 MB L2.
// Gather split into 4 feature-quarter block-groups, quarter = (bid&7)>>1,
// so under round-robin dispatch each XCD serves one quarter -> src row
// reads become L2 hits (attacks the ~26 G miss-lines/s fabric ceiling).
// Accumulation order per feature identical to R17 -> bit-identical output.

// Layer 1: scalar z agg + readlane matvec, W2 via LDS. Quarter-major out.
// grid NN/16.
__global__ __launch_bounds__(256) void k_l1(
    const float* __restrict__ xd, const float* __restrict__ dinv,
    const int* __restrict__ rowptr, const int2* __restrict__ ep,
    const float* __restrict__ W1, const float* __restrict__ b1,
    const float* __restrict__ W2, unsigned short* __restrict__ Gout)
{
    __shared__ float sW[4096];
    int tid = threadIdx.x;
    #pragma unroll
    for (int i = 0; i < 16; ++i) sW[tid + i * 256] = W2[tid + i * 256];
    __syncthreads();
    int lane = tid & 63, l16 = lane & 15, sub = lane >> 4;
    int g4 = blockIdx.x * 4 + (tid >> 6);
    int nodeS = g4 * 4 + sub;
    int beg = rowptr[nodeS], end = rowptr[nodeS + 1];
    float partial = 0.f;
    for (int idx = beg + l16; idx < end; idx += 16) {
        int2 p = ep[idx];
        partial = fmaf(__int_as_float(p.y), xd[p.x], partial);
    }
    #pragma unroll
    for (int m = 8; m >= 1; m >>= 1) partial += __shfl_xor(partial, m, 64);
    float z = dinv[nodeS] * (xd[nodeS] + partial);   // valid where l16==0
    float z0 = RLF(z, 0), z1 = RLF(z, 16), z2 = RLF(z, 32), z3 = RLF(z, 48);
    float w1l = W1[lane], b1l = b1[lane];
    float v0 = fmaxf(fmaf(z0, w1l, b1l), 0.f);
    float v1 = fmaxf(fmaf(z1, w1l, b1l), 0.f);
    float v2 = fmaxf(fmaf(z2, w1l, b1l), 0.f);
    float v3 = fmaxf(fmaf(z3, w1l, b1l), 0.f);
    float a0 = 0.f, a1 = 0.f, a2 = 0.f, a3 = 0.f;
    #pragma unroll
    for (int k = 0; k < 64; ++k) {
        float wk = sW[k * 64 + lane];
        a0 = fmaf(RLF(v0, k), wk, a0);
        a1 = fmaf(RLF(v1, k), wk, a1);
        a2 = fmaf(RLF(v2, k), wk, a2);
        a3 = fmaf(RLF(v3, k), wk, a3);
    }
    int n0 = g4 * 4;
    int qo = (lane >> 4) * (NN * 16) + l16;      // quarter-major ushort index
    Gout[qo + (n0 + 0) * 16] = bf16rtn(dinv[n0 + 0] * a0);
    Gout[qo + (n0 + 1) * 16] = bf16rtn(dinv[n0 + 1] * a1);
    Gout[qo + (n0 + 2) * 16] = bf16rtn(dinv[n0 + 2] * a2);
    Gout[qo + (n0 + 3) * 16] = bf16rtn(dinv[n0 + 3] * a3);
}

// Quarter gather: aggregate 16 features (quarter q) for 32 nodes/block,
// apply din+bias+relu, write v-quarter bf16. 8 nodes/wave, lane owns one
// dword (2 features) -> 64 rows in flight/wave. grid = 8*1563.
__global__ __launch_bounds__(256) void k_gq(
    const unsigned* __restrict__ Gq, const float* __restrict__ dinv,
    const int* __restrict__ rowptr, const int2* __restrict__ ep,
    const float* __restrict__ bias, unsigned* __restrict__ Yq)
{
    int bid = blockIdx.x;
    int q   = (bid & 7) >> 1;                 // feature quarter (XCD-pinned)
    int sub = bid & 1;
    int chunk = (bid >> 3) * 2 + sub;
    int node0 = chunk * 32;
    if (node0 >= NN) return;
    int tid = threadIdx.x;
    int lane = tid & 63;
    int q8 = lane >> 3;                       // node slot in wave
    int l8 = lane & 7;                        // dword slot in quarter row
    int node = node0 + (tid >> 6) * 8 + q8;
    const unsigned* G = Gq + (size_t)q * (NN * 8);
    int beg = rowptr[node], end = rowptr[node + 1];
    unsigned su = G[node * 8 + l8];
    float a0 = bflo(su), a1 = bfhi(su);
    int j = beg;
    for (; j + 8 <= end; j += 8) {            // full batch: 8 edges
        unsigned u[8]; float nv[8];
        #pragma unroll
        for (int t = 0; t < 8; ++t) {
            int2 p = ep[j + t];
            nv[t] = __int_as_float(p.y);
            u[t] = G[p.x * 8 + l8];
        }
        #pragma unroll
        for (int t = 0; t < 8; ++t) {
            a0 = fmaf(bflo(u[t]), nv[t], a0);
            a1 = fmaf(bfhi(u[t]), nv[t], a1);
        }
    }
    if (j < end) {                            // masked tail 1..7
        unsigned u[8]; float nv[8];
        #pragma unroll
        for (int t = 0; t < 8; ++t) {
            int idx = j + t;
            int2 p = ep[idx < end ? idx : j];
            nv[t] = (idx < end) ? __int_as_float(p.y) : 0.f;
            u[t] = G[p.x * 8 + l8];
        }
        #pragma unroll
        for (int t = 0; t < 8; ++t) {
            a0 = fmaf(bflo(u[t]), nv[t], a0);
            a1 = fmaf(bfhi(u[t]), nv[t], a1);
        }
    }
    float din = dinv[node];
    float2 bq = ((const float2*)bias)[q * 8 + l8];
    float v0 = fmaxf(fmaf(din, a0, bq.x), 0.f);
    float v1 = fmaxf(fmaf(din, a1, bq.y), 0.f);
    Yq[(size_t)q * (NN * 8) + node * 8 + l8] = bf16rtn2(v0, v1);
}

// Matvec: assemble v from 4 quarter regions, MFMA with Wf, write G'
// quarter-major. 8 nodes/wave; grid = NN/32.
__global__ __launch_bounds__(256) void k_mv2(
    const unsigned* __restrict__ Yq, const float* __restrict__ dinv,
    const unsigned* __restrict__ Wf, unsigned short* __restrict__ Gout)
{
    __shared__ __align__(16) unsigned sB[4096];
    __shared__ __align__(16) unsigned sA[4][256];
    int tid = threadIdx.x;
    #pragma unroll
    for (int i = 0; i < 4; ++i)
        ((v4u*)sB)[tid + i * 256] = ((const v4u*)Wf)[tid + i * 256];
    int lane = tid & 63;
    int wid  = tid >> 6;
    int q8   = lane >> 3;
    int l8   = lane & 7;
    int n0 = (blockIdx.x * 4 + wid) * 8;
    int node = n0 + q8;
    #pragma unroll
    for (int r = 0; r < 4; ++r)
        sA[wid][q8 * 32 + r * 8 + l8] = Yq[(size_t)r * (NN * 8) + node * 8 + l8];
    __syncthreads();
    int rr  = lane & 7;
    int blk = lane >> 4;
    v8s fa0 = *(const v8s*)&sA[wid][rr * 32 +  0 + blk * 4];
    v8s fa1 = *(const v8s*)&sA[wid][rr * 32 + 16 + blk * 4];
    v4f acc[4];
    #pragma unroll
    for (int nt = 0; nt < 4; ++nt) {
        v8s bh0 = *(const v8s*)&sB[((0 * 4 + nt) * 64 + lane) * 4];
        v8s bh1 = *(const v8s*)&sB[((1 * 4 + nt) * 64 + lane) * 4];
        v8s bl0 = *(const v8s*)&sB[((2 * 4 + nt) * 64 + lane) * 4];
        v8s bl1 = *(const v8s*)&sB[((3 * 4 + nt) * 64 + lane) * 4];
        v4f c = {0.f, 0.f, 0.f, 0.f};
        c = __builtin_amdgcn_mfma_f32_16x16x32_bf16(fa0, bl0, c, 0, 0, 0);
        c = __builtin_amdgcn_mfma_f32_16x16x32_bf16(fa1, bl1, c, 0, 0, 0);
        c = __builtin_amdgcn_mfma_f32_16x16x32_bf16(fa0, bh0, c, 0, 0, 0);
        c = __builtin_amdgcn_mfma_f32_16x16x32_bf16(fa1, bh1, c, 0, 0, 0);
        acc[nt] = c;
    }
    // C: col = lane&15, row = (lane>>4)*4 + reg. Rows 0-7 = nodes.
    int grp = lane >> 4;
    int l16 = lane & 15;
    if (grp < 2) {
        int rb = grp * 4;
        float4 dn = *(const float4*)&dinv[n0 + rb];
        #pragma unroll
        for (int r = 0; r < 4; ++r) {
            float d = (r == 0) ? dn.x : (r == 1) ? dn.y : (r == 2) ? dn.z : dn.w;
            #pragma unroll
            for (int nt = 0; nt < 4; ++nt)
                Gout[nt * (NN * 16) + (n0 + rb + r) * 16 + l16] =
                    bf16rtn(d * acc[nt][r]);
        }
    }
}

// Head: assemble layer-5 v from quarters, fW1 MFMA, relu, fW2 dot, out.
// 8 nodes/wave; grid = NN/32.
__global__ __launch_bounds__(256) void k_head2(
    const unsigned* __restrict__ Yq, const unsigned* __restrict__ Wf,
    const float* __restrict__ fb1, const float* __restrict__ fW2,
    const float* __restrict__ fb2, float* __restrict__ out)
{
    __shared__ __align__(16) unsigned sB[4096];
    __shared__ __align__(16) unsigned sA[4][256];
    int tid = threadIdx.x;
    #pragma unroll
    for (int i = 0; i < 4; ++i)
        ((v4u*)sB)[tid + i * 256] = ((const v4u*)Wf)[tid + i * 256];
    int lane = tid & 63;
    int wid  = tid >> 6;
    int q8   = lane >> 3;
    int l8   = lane & 7;
    int l16  = lane & 15;
    int n0 = (blockIdx.x * 4 + wid) * 8;
    int node = n0 + q8;
    float fb1v[4], fw2v[4];
    #pragma unroll
    for (int nt = 0; nt < 4; ++nt) {
        fb1v[nt] = fb1[nt * 16 + l16];
        fw2v[nt] = fW2[nt * 16 + l16];
    }
    float fb2s = fb2[0];
    #pragma unroll
    for (int r = 0; r < 4; ++r)
        sA[wid][q8 * 32 + r * 8 + l8] = Yq[(size_t)r * (NN * 8) + node * 8 + l8];
    __syncthreads();
    int rr  = lane & 7;
    int blk = lane >> 4;
    v8s fa0 = *(const v8s*)&sA[wid][rr * 32 +  0 + blk * 4];
    v8s fa1 = *(const v8s*)&sA[wid][rr * 32 + 16 + blk * 4];
    v4f acc[4];
    #pragma unroll
    for (int nt = 0; nt < 4; ++nt) {
        v8s bh0 = *(const v8s*)&sB[((0 * 4 + nt) * 64 + lane) * 4];
        v8s bh1 = *(const v8s*)&sB[((1 * 4 + nt) * 64 + lane) * 4];
        v8s bl0 = *(const v8s*)&sB[((2 * 4 + nt) * 64 + lane) * 4];
        v8s bl1 = *(const v8s*)&sB[((3 * 4 + nt) * 64 + lane) * 4];
        v4f c = {0.f, 0.f, 0.f, 0.f};
        c = __builtin_amdgcn_mfma_f32_16x16x32_bf16(fa0, bl0, c, 0, 0, 0);
        c = __builtin_amdgcn_mfma_f32_16x16x32_bf16(fa1, bl1, c, 0, 0, 0);
        c = __builtin_amdgcn_mfma_f32_16x16x32_bf16(fa0, bh0, c, 0, 0, 0);
        c = __builtin_amdgcn_mfma_f32_16x16x32_bf16(fa1, bh1, c, 0, 0, 0);
        acc[nt] = c;
    }
    // lanes 0-15: nodes n0+0..3 (regs 0-3); lanes 16-31: nodes n0+4..7.
    float tr[4];
    #pragma unroll
    for (int r = 0; r < 4; ++r) {
        float t = 0.f;
        #pragma unroll
        for (int nt = 0; nt < 4; ++nt)
            t += fmaxf(acc[nt][r] + fb1v[nt], 0.f) * fw2v[nt];
        #pragma unroll
        for (int m = 8; m >= 1; m >>= 1) t += __shfl_xor(t, m, 64);
        tr[r] = t;
    }
    if (lane == 0) {
        float4 o = {tr[0] + fb2s, tr[1] + fb2s, tr[2] + fb2s, tr[3] + fb2s};
        *(float4*)&out[n0] = o;
    } else if (lane == 16) {
        float4 o = {tr[0] + fb2s, tr[1] + fb2s, tr[2] + fb2s, tr[3] + fb2s};
        *(float4*)&out[n0 + 4] = o;
    }
}

// ---------------- Launch ----------------

extern "C" void kernel_launch(void* const* d_in, const int* in_sizes, int n_in,
                              void* d_out, int out_size, void* d_ws, size_t ws_size,
                              hipStream_t stream) {
    const float* x   = (const float*)d_in[0];
    const int*   ei  = (const int*)d_in[1];
    const float* ew  = (const float*)d_in[2];
    const float* W1  = (const float*)d_in[3];
    const float* b1  = (const float*)d_in[4];
    const float* W2  = (const float*)d_in[5];
    const float* b2  = (const float*)d_in[6];
    const float* W3  = (const float*)d_in[7];
    const float* b3  = (const float*)d_in[8];
    const float* W4  = (const float*)d_in[9];
    const float* b4  = (const float*)d_in[10];
    const float* W5  = (const float*)d_in[11];
    const float* b5  = (const float*)d_in[12];
    const float* fW1 = (const float*)d_in[13];
    const float* fb1 = (const float*)d_in[14];
    const float* fW2 = (const float*)d_in[15];
    const float* fb2 = (const float*)d_in[16];
    float* out = (float*)d_out;

    char* ws = (char*)d_ws;
    size_t o = 0;
    auto alloc = [&](size_t elems) -> void* {
        void* p = (void*)(ws + o);
        o += ((elems * 4 + 255) / 256) * 256;
        return p;
    };
    float* dinv   = (float*)alloc(NN);
    float* xd     = (float*)alloc(NN);
    int*   rowptr = (int*)alloc(NN + 1);
    unsigned long long* cnt64 = (unsigned long long*)alloc(2 * (size_t)NN);
    int*   bsum   = (int*)alloc(128);
    int2*  epair  = (int2*)alloc(2 * (size_t)EE);
    unsigned* Ga16 = (unsigned*)alloc((size_t)NN * 32);   // quarter-major G'
    unsigned* Gb16 = (unsigned*)alloc((size_t)NN * 32);
    unsigned* Yq   = (unsigned*)alloc((size_t)NN * 32);   // quarter-major v
    int*   slot   = (int*)Yq;          // slot dead before Yq first written
    unsigned* Wf  = (unsigned*)alloc(4 * 4096);           // pre-packed W frags

    int gE  = (EE + 255) / 256;
    int nb  = (NN + 1023) / 1024;    // 98
    int gW4 = NN / 16;               // 6250: k_l1
    int gW8 = NN / 32;               // 3125: k_mv2 / k_head2
    int gQ  = 8 * 1563;              // 12504: quarter gather (4q x 2 XCD-lanes)

    k_wpk<<<4, 256, 0, stream>>>(W3, W4, W5, fW1, Wf);
    hipMemsetAsync(cnt64, 0, NN * sizeof(unsigned long long), stream);
    k_count<<<gE, 256, 0, stream>>>(ei, ew, cnt64, slot);
    k_bsum<<<nb, 256, 0, stream>>>(cnt64, bsum);
    k_scan_out<<<nb, 256, 0, stream>>>(cnt64, bsum, x, rowptr, dinv, xd);
    k_fill<<<gE, 256, 0, stream>>>(ei, ew, slot, rowptr, epair);

    // Layer 1 -> G2' (quarter-major bf16)
    k_l1<<<gW4, 256, 0, stream>>>(xd, dinv, rowptr, epair, W1, b1, W2,
                                  (unsigned short*)Ga16);
    // Layers 2..4: quarter gather (XCD-L2-resident) + MFMA matvec
    k_gq<<<gQ, 256, 0, stream>>>(Ga16, dinv, rowptr, epair, b2, Yq);
    k_mv2<<<gW8, 256, 0, stream>>>(Yq, dinv, Wf + 0, (unsigned short*)Gb16);
    k_gq<<<gQ, 256, 0, stream>>>(Gb16, dinv, rowptr, epair, b3, Yq);
    k_mv2<<<gW8, 256, 0, stream>>>(Yq, dinv, Wf + 4096, (unsigned short*)Ga16);
    k_gq<<<gQ, 256, 0, stream>>>(Ga16, dinv, rowptr, epair, b4, Yq);
    k_mv2<<<gW8, 256, 0, stream>>>(Yq, dinv, Wf + 8192, (unsigned short*)Gb16);
    // Layer 5 + head
    k_gq<<<gQ, 256, 0, stream>>>(Gb16, dinv, rowptr, epair, b5, Yq);
    k_head2<<<gW8, 256, 0, stream>>>(Yq, Wf + 12288, fb1, fW2, fb2, out);
}

// Round 10
// 351.083 us; speedup vs baseline: 1.3310x; 1.3310x over previous
//
#include <hip/hip_runtime.h>
#include <hip/hip_bf16.h>

#define NN 100000
#define EE 1250000

#define RL(x, l) __builtin_amdgcn_readlane((x), (l))
#define RLF(x, l) __int_as_float(__builtin_amdgcn_readlane(__float_as_int(x), (l)))

typedef __attribute__((ext_vector_type(8))) short v8s;
typedef __attribute__((ext_vector_type(4))) float v4f;
typedef __attribute__((ext_vector_type(4))) unsigned int v4u;

__device__ __forceinline__ unsigned short bf16rtn(float x) {
    unsigned u = __float_as_uint(x);
    unsigned r = u + 0x7fffu + ((u >> 16) & 1u);
    return (unsigned short)(r >> 16);
}
__device__ __forceinline__ unsigned bf16rtn2(float lo, float hi) {
    return (unsigned)bf16rtn(lo) | ((unsigned)bf16rtn(hi) << 16);
}
__device__ __forceinline__ float bflo(unsigned u) { return __uint_as_float(u << 16); }
__device__ __forceinline__ float bfhi(unsigned u) { return __uint_as_float(u & 0xffff0000u); }
__device__ __forceinline__ float bfs(unsigned short s) { return __uint_as_float((unsigned)s << 16); }

// ---------------- CSR build (packed; R9-proven) ----------------
// Atomic pass: ~23 G TRANSACTIONS/s memory-side atomic ceiling (R2..R10).
// R18 lesson: even non-returning atomicAdd costs a fabric transaction +
// 64B write-through (zacc folding reverted). R19 lesson: feature-quarter
// XCD pinning re-reads ep 4x -> regression; reverted.
// R15 (kept): k_deg folded into k_count's 64-bit packed atomic.

__global__ __launch_bounds__(256) void k_count(const int* __restrict__ ei,
                                               const float* __restrict__ ew,
                                               unsigned long long* __restrict__ cnt,
                                               int* __restrict__ slot) {
    int e = blockIdx.x * 256 + threadIdx.x;
    if (e >= EE) return;
    int d = __builtin_nontemporal_load(&ei[EE + e]);
    float w = __builtin_nontemporal_load(&ew[e]);
    unsigned fx = (unsigned)(w * 16777216.0f + 0.5f);   // w in [0,1] -> <= 2^24
    unsigned long long old =
        atomicAdd(&cnt[d], (1ULL << 32) | (unsigned long long)fx);
    __builtin_nontemporal_store((int)(old >> 32), &slot[e]);
}

__global__ __launch_bounds__(256) void k_bsum(const unsigned long long* __restrict__ cnt,
                                              int* __restrict__ bsum) {
    __shared__ int ls[256];
    int b = blockIdx.x, tid = threadIdx.x;
    int base = b * 1024 + tid * 4;
    int s = 0;
    #pragma unroll
    for (int j = 0; j < 4; ++j) { int g = base + j; if (g < NN) s += (int)(cnt[g] >> 32); }
    ls[tid] = s; __syncthreads();
    for (int off = 128; off > 0; off >>= 1) {
        if (tid < off) ls[tid] += ls[tid + off];
        __syncthreads();
    }
    if (tid == 0) bsum[b] = ls[0];
}

__global__ __launch_bounds__(256) void k_scan_out(const unsigned long long* __restrict__ cnt,
                                                  const int* __restrict__ bsum,
                                                  const float* __restrict__ x,
                                                  int* __restrict__ rowptr,
                                                  float* __restrict__ dinv,
                                                  float* __restrict__ xd) {
    __shared__ int ls[256];
    __shared__ int sbase;
    int b = blockIdx.x, tid = threadIdx.x;
    if (tid < 64) {
        int w0 = (tid < b) ? bsum[tid] : 0;
        int w1 = ((64 + tid) < b) ? bsum[64 + tid] : 0;
        int s = w0 + w1;
        #pragma unroll
        for (int m = 32; m >= 1; m >>= 1) s += __shfl_xor(s, m, 64);
        if (tid == 0) sbase = s;
    }
    int base = b * 1024 + tid * 4;
    int c[4]; float sw[4]; int s = 0;
    #pragma unroll
    for (int j = 0; j < 4; ++j) {
        int g = base + j;
        unsigned long long v = (g < NN) ? cnt[g] : 0ULL;
        c[j] = (int)(v >> 32);
        sw[j] = (float)(unsigned)(v & 0xffffffffu) * (1.0f / 16777216.0f);
        s += c[j];
    }
    ls[tid] = s; __syncthreads();
    for (int off = 1; off < 256; off <<= 1) {
        int v = (tid >= off) ? ls[tid - off] : 0;
        __syncthreads();
        ls[tid] += v;
        __syncthreads();
    }
    int excl = ls[tid] - s + sbase;
    #pragma unroll
    for (int j = 0; j < 4; ++j) {
        int g = base + j;
        if (g < NN) {
            rowptr[g + 1] = excl + c[j];
            excl += c[j];
            float di = rsqrtf(sw[j] + 1.0f);
            dinv[g] = di;
            xd[g] = di * x[g];
        }
    }
    if (b == 0 && tid == 0) rowptr[0] = 0;
}

__global__ __launch_bounds__(256) void k_fill(const int* __restrict__ ei,
                                              const float* __restrict__ ew,
                                              const int* __restrict__ slot,
                                              const int* __restrict__ rowptr,
                                              int2* __restrict__ epair) {
    int e = blockIdx.x * 256 + threadIdx.x;
    if (e >= EE) return;
    int s = __builtin_nontemporal_load(&ei[e]);
    int d = __builtin_nontemporal_load(&ei[EE + e]);
    float w = __builtin_nontemporal_load(&ew[e]);
    int sl = __builtin_nontemporal_load(&slot[e]);
    int p = rowptr[d] + sl;
    epair[p] = make_int2(s, __float_as_int(w));
}

// ---------------- W pre-pack for MFMA (R12, R13-fixed) ----------------
// Packs 64x64 fp32 W into mfma_f32_16x16x32_bf16 B-fragment order, SPLIT
// hi+lo bf16 (fp32-equivalent W). 16 KB per W. R13: 512 slots (i<2).
// R20: 5 blocks: {W2, W3, W4, W5, fW1}.
__global__ __launch_bounds__(256) void k_wpk(const float* __restrict__ Wa,
                                             const float* __restrict__ Wb,
                                             const float* __restrict__ Wc,
                                             const float* __restrict__ Wd,
                                             const float* __restrict__ We,
                                             unsigned* __restrict__ Wf) {
    const float* W = (blockIdx.x == 0) ? Wa : (blockIdx.x == 1) ? Wb
                   : (blockIdx.x == 2) ? Wc : (blockIdx.x == 3) ? Wd : We;
    unsigned* out = Wf + blockIdx.x * 4096;
    int t = threadIdx.x;
    #pragma unroll
    for (int i = 0; i < 2; ++i) {
        int s = t * 2 + i;
        int lane = s & 63;
        int nt = (s >> 6) & 3;
        int kt = s >> 8;                 // 0..1
        int col = nt * 16 + (lane & 15);
        int k0 = kt * 32 + (lane >> 4) * 8;
        unsigned hi[4], lo[4];
        #pragma unroll
        for (int d = 0; d < 4; ++d) {
            float w0 = W[(k0 + 2 * d) * 64 + col];
            float w1 = W[(k0 + 2 * d + 1) * 64 + col];
            unsigned short h0 = bf16rtn(w0), h1 = bf16rtn(w1);
            float r0 = w0 - bfs(h0), r1 = w1 - bfs(h1);
            hi[d] = (unsigned)h0 | ((unsigned)h1 << 16);
            lo[d] = (unsigned)bf16rtn(r0) | ((unsigned)bf16rtn(r1) << 16);
        }
        int gh = (0 * 2 + kt) * 4 + nt;
        int gl = (1 * 2 + kt) * 4 + nt;
        *(v4u*)&out[(gh * 64 + lane) * 4] = (v4u){hi[0], hi[1], hi[2], hi[3]};
        *(v4u*)&out[(gl * 64 + lane) * 4] = (v4u){lo[0], lo[1], lo[2], lo[3]};
    }
}

// ---------------- Eighth-wave gather (R17) ----------------
// One node per 8-lane group; lane owns 8 features via one uint4 (16B) load
// per edge -> one load instr fetches 8 rows, 64 rows in flight per wave.
// At ~26 G L2-miss-lines/s this sits at the fabric transaction ceiling
// (R14 compiler-ILP null, R16/R17 structural-MLP converged, R19 locality
// regression bracket it as the floor for random 128B row access).
__device__ __forceinline__ void gatherq8(
    const unsigned* __restrict__ G16, const int2* __restrict__ ep,
    int node, int beg, int end, int l8, float a[8])
{
    uint4 su = *(const uint4*)&G16[node * 32 + l8 * 4];
    a[0] = bflo(su.x); a[1] = bfhi(su.x);
    a[2] = bflo(su.y); a[3] = bfhi(su.y);
    a[4] = bflo(su.z); a[5] = bfhi(su.z);
    a[6] = bflo(su.w); a[7] = bfhi(su.w);
    int j = beg;
    for (; j + 8 <= end; j += 8) {            // full batch: 8 edges
        uint4 u[8]; float nv[8];
        #pragma unroll
        for (int t = 0; t < 8; ++t) {
            int2 p = ep[j + t];
            nv[t] = __int_as_float(p.y);
            u[t] = *(const uint4*)&G16[p.x * 32 + l8 * 4];
        }
        #pragma unroll
        for (int t = 0; t < 8; ++t) {
            a[0] = fmaf(bflo(u[t].x), nv[t], a[0]);
            a[1] = fmaf(bfhi(u[t].x), nv[t], a[1]);
            a[2] = fmaf(bflo(u[t].y), nv[t], a[2]);
            a[3] = fmaf(bfhi(u[t].y), nv[t], a[3]);
            a[4] = fmaf(bflo(u[t].z), nv[t], a[4]);
            a[5] = fmaf(bfhi(u[t].z), nv[t], a[5]);
            a[6] = fmaf(bflo(u[t].w), nv[t], a[6]);
            a[7] = fmaf(bfhi(u[t].w), nv[t], a[7]);
        }
    }
    if (j < end) {                            // masked tail 1..7
        uint4 u[8]; float nv[8];
        #pragma unroll
        for (int t = 0; t < 8; ++t) {
            int idx = j + t;
            int2 p = ep[idx < end ? idx : j];
            nv[t] = (idx < end) ? __int_as_float(p.y) : 0.f;
            u[t] = *(const uint4*)&G16[p.x * 32 + l8 * 4];
        }
        #pragma unroll
        for (int t = 0; t < 8; ++t) {
            a[0] = fmaf(bflo(u[t].x), nv[t], a[0]);
            a[1] = fmaf(bfhi(u[t].x), nv[t], a[1]);
            a[2] = fmaf(bflo(u[t].y), nv[t], a[2]);
            a[3] = fmaf(bfhi(u[t].y), nv[t], a[3]);
            a[4] = fmaf(bflo(u[t].z), nv[t], a[4]);
            a[5] = fmaf(bfhi(u[t].z), nv[t], a[5]);
            a[6] = fmaf(bflo(u[t].w), nv[t], a[6]);
            a[7] = fmaf(bfhi(u[t].w), nv[t], a[7]);
        }
    }
}

// ---------------- Layers ----------------
// Identity: Agg_l[d] = dinv_d * ( G'_l[d] + sum_e w_e * G'_l[src] ).
// G' stored bf16 row-major (32 dwords = 128 B/node). Accumulation fp32.
// R12/R13: matvec on MFMA. R17: 8 nodes/wave. R20: k_l1 moved to the same
// 8-node/wave MFMA structure (was the last readlane/VALU matvec, ~27us).

// Layer 1 (R20): 8-lane-group scalar z aggregation (stride-8 edge loop +
// intra-group shfl reduce) + relu(z*W1+b1) per-lane 8 features + MFMA W2
// tail (R18-proven). grid NN/32.
__global__ __launch_bounds__(256) void k_l1(
    const float* __restrict__ xd, const float* __restrict__ dinv,
    const int* __restrict__ rowptr, const int2* __restrict__ ep,
    const float* __restrict__ W1, const float* __restrict__ b1,
    const unsigned* __restrict__ Wf, unsigned short* __restrict__ Gout)
{
    __shared__ __align__(16) unsigned sB[4096];
    __shared__ __align__(16) unsigned sA[4][256];
    int tid = threadIdx.x;
    #pragma unroll
    for (int i = 0; i < 4; ++i)
        ((v4u*)sB)[tid + i * 256] = ((const v4u*)Wf)[tid + i * 256];
    int lane = tid & 63;
    int wid  = tid >> 6;
    int q8   = lane >> 3;
    int l8   = lane & 7;
    int n0 = (blockIdx.x * 4 + wid) * 8;
    int node = n0 + q8;
    int beg = rowptr[node], end = rowptr[node + 1];
    float partial = 0.f;
    for (int idx = beg + l8; idx < end; idx += 8) {
        int2 p = ep[idx];
        partial = fmaf(__int_as_float(p.y), xd[p.x], partial);
    }
    partial += __shfl_xor(partial, 1, 64);    // reduce across the 8-lane group
    partial += __shfl_xor(partial, 2, 64);
    partial += __shfl_xor(partial, 4, 64);
    float z = dinv[node] * (xd[node] + partial);
    float4 wa = ((const float4*)W1)[l8 * 2];
    float4 wb = ((const float4*)W1)[l8 * 2 + 1];
    float4 ba = ((const float4*)b1)[l8 * 2];
    float4 bb = ((const float4*)b1)[l8 * 2 + 1];
    float v0 = fmaxf(fmaf(z, wa.x, ba.x), 0.f);
    float v1 = fmaxf(fmaf(z, wa.y, ba.y), 0.f);
    float v2 = fmaxf(fmaf(z, wa.z, ba.z), 0.f);
    float v3 = fmaxf(fmaf(z, wa.w, ba.w), 0.f);
    float v4 = fmaxf(fmaf(z, wb.x, bb.x), 0.f);
    float v5 = fmaxf(fmaf(z, wb.y, bb.y), 0.f);
    float v6 = fmaxf(fmaf(z, wb.z, bb.z), 0.f);
    float v7 = fmaxf(fmaf(z, wb.w, bb.w), 0.f);
    *(uint4*)&sA[wid][q8 * 32 + l8 * 4] = make_uint4(
        bf16rtn2(v0, v1), bf16rtn2(v2, v3),
        bf16rtn2(v4, v5), bf16rtn2(v6, v7));
    __syncthreads();
    int rr  = lane & 7;
    int blk = lane >> 4;
    v8s fa0 = *(const v8s*)&sA[wid][rr * 32 +  0 + blk * 4];
    v8s fa1 = *(const v8s*)&sA[wid][rr * 32 + 16 + blk * 4];
    v4f acc[4];
    #pragma unroll
    for (int nt = 0; nt < 4; ++nt) {
        v8s bh0 = *(const v8s*)&sB[((0 * 4 + nt) * 64 + lane) * 4];
        v8s bh1 = *(const v8s*)&sB[((1 * 4 + nt) * 64 + lane) * 4];
        v8s bl0 = *(const v8s*)&sB[((2 * 4 + nt) * 64 + lane) * 4];
        v8s bl1 = *(const v8s*)&sB[((3 * 4 + nt) * 64 + lane) * 4];
        v4f c = {0.f, 0.f, 0.f, 0.f};
        c = __builtin_amdgcn_mfma_f32_16x16x32_bf16(fa0, bl0, c, 0, 0, 0);
        c = __builtin_amdgcn_mfma_f32_16x16x32_bf16(fa1, bl1, c, 0, 0, 0);
        c = __builtin_amdgcn_mfma_f32_16x16x32_bf16(fa0, bh0, c, 0, 0, 0);
        c = __builtin_amdgcn_mfma_f32_16x16x32_bf16(fa1, bh1, c, 0, 0, 0);
        acc[nt] = c;
    }
    int grp = lane >> 4;
    int l16 = lane & 15;
    if (grp < 2) {
        int rb = grp * 4;
        float4 dn = *(const float4*)&dinv[n0 + rb];
        #pragma unroll
        for (int r = 0; r < 4; ++r) {
            float d = (r == 0) ? dn.x : (r == 1) ? dn.y : (r == 2) ? dn.z : dn.w;
            #pragma unroll
            for (int nt = 0; nt < 4; ++nt)
                Gout[(n0 + rb + r) * 64 + nt * 16 + l16] = bf16rtn(d * acc[nt][r]);
        }
    }
}

// Fused eighth-wave gather + bias/relu + MFMA matvec + dinv scale
// (layers 2..4). 8 nodes/wave; grid = NN/32.
__global__ __launch_bounds__(256) void k_gmv(
    const unsigned* __restrict__ G16, const float* __restrict__ dinv,
    const int* __restrict__ rowptr, const int2* __restrict__ ep,
    const float* __restrict__ bias, const unsigned* __restrict__ Wf,
    unsigned short* __restrict__ Gout)
{
    __shared__ __align__(16) unsigned sB[4096];   // 16 KB: Whi/Wlo fragments
    __shared__ __align__(16) unsigned sA[4][256]; // per-wave A scratch (8n x 32dw)
    int tid = threadIdx.x;
    #pragma unroll
    for (int i = 0; i < 4; ++i)
        ((v4u*)sB)[tid + i * 256] = ((const v4u*)Wf)[tid + i * 256];
    int lane = tid & 63;
    int wid  = tid >> 6;
    int q    = lane >> 3;                         // node slot 0..7
    int l8   = lane & 7;
    int n0 = (blockIdx.x * 4 + wid) * 8;
    int node = n0 + q;
    int beg = rowptr[node], end = rowptr[node + 1];
    float a[8];
    gatherq8(G16, ep, node, beg, end, l8, a);
    float din = dinv[node];
    float4 bv0 = ((const float4*)bias)[l8 * 2];   // features 8*l8..+3
    float4 bv1 = ((const float4*)bias)[l8 * 2 + 1];
    float v0 = fmaxf(fmaf(din, a[0], bv0.x), 0.f);
    float v1 = fmaxf(fmaf(din, a[1], bv0.y), 0.f);
    float v2 = fmaxf(fmaf(din, a[2], bv0.z), 0.f);
    float v3 = fmaxf(fmaf(din, a[3], bv0.w), 0.f);
    float v4 = fmaxf(fmaf(din, a[4], bv1.x), 0.f);
    float v5 = fmaxf(fmaf(din, a[5], bv1.y), 0.f);
    float v6 = fmaxf(fmaf(din, a[6], bv1.z), 0.f);
    float v7 = fmaxf(fmaf(din, a[7], bv1.w), 0.f);
    *(uint4*)&sA[wid][q * 32 + l8 * 4] = make_uint4(
        bf16rtn2(v0, v1), bf16rtn2(v2, v3),
        bf16rtn2(v4, v5), bf16rtn2(v6, v7));      // k-pairs (8l8..8l8+7)
    __syncthreads();                              // sB ready (sA wave-local)
    // ---- matvec on MFMA pipe (A rows 0-7 = nodes; 8-15 dup) ----
    int rr  = lane & 7;
    int blk = lane >> 4;
    v8s fa0 = *(const v8s*)&sA[wid][rr * 32 +  0 + blk * 4];   // kt=0
    v8s fa1 = *(const v8s*)&sA[wid][rr * 32 + 16 + blk * 4];   // kt=1
    v4f acc[4];
    #pragma unroll
    for (int nt = 0; nt < 4; ++nt) {
        v8s bh0 = *(const v8s*)&sB[((0 * 4 + nt) * 64 + lane) * 4];  // h=0 kt=0
        v8s bh1 = *(const v8s*)&sB[((1 * 4 + nt) * 64 + lane) * 4];  // h=0 kt=1
        v8s bl0 = *(const v8s*)&sB[((2 * 4 + nt) * 64 + lane) * 4];  // h=1 kt=0
        v8s bl1 = *(const v8s*)&sB[((3 * 4 + nt) * 64 + lane) * 4];  // h=1 kt=1
        v4f c = {0.f, 0.f, 0.f, 0.f};
        c = __builtin_amdgcn_mfma_f32_16x16x32_bf16(fa0, bl0, c, 0, 0, 0);
        c = __builtin_amdgcn_mfma_f32_16x16x32_bf16(fa1, bl1, c, 0, 0, 0);
        c = __builtin_amdgcn_mfma_f32_16x16x32_bf16(fa0, bh0, c, 0, 0, 0);
        c = __builtin_amdgcn_mfma_f32_16x16x32_bf16(fa1, bh1, c, 0, 0, 0);
        acc[nt] = c;
    }
    // C: col = lane&15, row = (lane>>4)*4 + reg. Rows 0-3 -> lanes 0-15,
    // rows 4-7 -> lanes 16-31 (rows 8-15 = dup, lanes 32-63 idle here).
    int grp = lane >> 4;
    int l16 = lane & 15;
    if (grp < 2) {
        int rb = grp * 4;
        float4 dn = *(const float4*)&dinv[n0 + rb];
        #pragma unroll
        for (int r = 0; r < 4; ++r) {
            float d = (r == 0) ? dn.x : (r == 1) ? dn.y : (r == 2) ? dn.z : dn.w;
            #pragma unroll
            for (int nt = 0; nt < 4; ++nt)
                Gout[(n0 + rb + r) * 64 + nt * 16 + l16] = bf16rtn(d * acc[nt][r]);
        }
    }
}

// Fused eighth-wave gather + layer-5 bias/relu + head (fW1 MFMA, relu,
// fW2 dot). 8 nodes/wave; grid = NN/32.
__global__ __launch_bounds__(256) void k_ghead(
    const unsigned* __restrict__ G16, const float* __restrict__ dinv,
    const int* __restrict__ rowptr, const int2* __restrict__ ep,
    const float* __restrict__ b5, const unsigned* __restrict__ Wf,
    const float* __restrict__ fb1, const float* __restrict__ fW2,
    const float* __restrict__ fb2, float* __restrict__ out)
{
    __shared__ __align__(16) unsigned sB[4096];
    __shared__ __align__(16) unsigned sA[4][256];
    int tid = threadIdx.x;
    #pragma unroll
    for (int i = 0; i < 4; ++i)
        ((v4u*)sB)[tid + i * 256] = ((const v4u*)Wf)[tid + i * 256];
    int lane = tid & 63;
    int wid  = tid >> 6;
    int q    = lane >> 3;
    int l8   = lane & 7;
    int l16  = lane & 15;
    int n0 = (blockIdx.x * 4 + wid) * 8;
    int node = n0 + q;
    float fb1v[4], fw2v[4];
    #pragma unroll
    for (int nt = 0; nt < 4; ++nt) {
        fb1v[nt] = fb1[nt * 16 + l16];
        fw2v[nt] = fW2[nt * 16 + l16];
    }
    float fb2s = fb2[0];
    int beg = rowptr[node], end = rowptr[node + 1];
    float a[8];
    gatherq8(G16, ep, node, beg, end, l8, a);
    float din = dinv[node];
    float4 bv0 = ((const float4*)b5)[l8 * 2];
    float4 bv1 = ((const float4*)b5)[l8 * 2 + 1];
    float v0 = fmaxf(fmaf(din, a[0], bv0.x), 0.f);
    float v1 = fmaxf(fmaf(din, a[1], bv0.y), 0.f);
    float v2 = fmaxf(fmaf(din, a[2], bv0.z), 0.f);
    float v3 = fmaxf(fmaf(din, a[3], bv0.w), 0.f);
    float v4 = fmaxf(fmaf(din, a[4], bv1.x), 0.f);
    float v5 = fmaxf(fmaf(din, a[5], bv1.y), 0.f);
    float v6 = fmaxf(fmaf(din, a[6], bv1.z), 0.f);
    float v7 = fmaxf(fmaf(din, a[7], bv1.w), 0.f);
    *(uint4*)&sA[wid][q * 32 + l8 * 4] = make_uint4(
        bf16rtn2(v0, v1), bf16rtn2(v2, v3),
        bf16rtn2(v4, v5), bf16rtn2(v6, v7));
    __syncthreads();
    int rr  = lane & 7;
    int blk = lane >> 4;
    v8s fa0 = *(const v8s*)&sA[wid][rr * 32 +  0 + blk * 4];
    v8s fa1 = *(const v8s*)&sA[wid][rr * 32 + 16 + blk * 4];
    v4f acc[4];
    #pragma unroll
    for (int nt = 0; nt < 4; ++nt) {
        v8s bh0 = *(const v8s*)&sB[((0 * 4 + nt) * 64 + lane) * 4];
        v8s bh1 = *(const v8s*)&sB[((1 * 4 + nt) * 64 + lane) * 4];
        v8s bl0 = *(const v8s*)&sB[((2 * 4 + nt) * 64 + lane) * 4];
        v8s bl1 = *(const v8s*)&sB[((3 * 4 + nt) * 64 + lane) * 4];
        v4f c = {0.f, 0.f, 0.f, 0.f};
        c = __builtin_amdgcn_mfma_f32_16x16x32_bf16(fa0, bl0, c, 0, 0, 0);
        c = __builtin_amdgcn_mfma_f32_16x16x32_bf16(fa1, bl1, c, 0, 0, 0);
        c = __builtin_amdgcn_mfma_f32_16x16x32_bf16(fa0, bh0, c, 0, 0, 0);
        c = __builtin_amdgcn_mfma_f32_16x16x32_bf16(fa1, bh1, c, 0, 0, 0);
        acc[nt] = c;
    }
    // lanes 0-15: nodes n0+0..3 (regs 0-3); lanes 16-31: nodes n0+4..7.
    float tr[4];
    #pragma unroll
    for (int r = 0; r < 4; ++r) {
        float t = 0.f;
        #pragma unroll
        for (int nt = 0; nt < 4; ++nt)
            t += fmaxf(acc[nt][r] + fb1v[nt], 0.f) * fw2v[nt];
        #pragma unroll
        for (int m = 8; m >= 1; m >>= 1) t += __shfl_xor(t, m, 64);
        tr[r] = t;
    }
    if (lane == 0) {
        float4 o = {tr[0] + fb2s, tr[1] + fb2s, tr[2] + fb2s, tr[3] + fb2s};
        *(float4*)&out[n0] = o;
    } else if (lane == 16) {
        float4 o = {tr[0] + fb2s, tr[1] + fb2s, tr[2] + fb2s, tr[3] + fb2s};
        *(float4*)&out[n0 + 4] = o;
    }
}

// ---------------- Launch ----------------

extern "C" void kernel_launch(void* const* d_in, const int* in_sizes, int n_in,
                              void* d_out, int out_size, void* d_ws, size_t ws_size,
                              hipStream_t stream) {
    const float* x   = (const float*)d_in[0];
    const int*   ei  = (const int*)d_in[1];
    const float* ew  = (const float*)d_in[2];
    const float* W1  = (const float*)d_in[3];
    const float* b1  = (const float*)d_in[4];
    const float* W2  = (const float*)d_in[5];
    const float* b2  = (const float*)d_in[6];
    const float* W3  = (const float*)d_in[7];
    const float* b3  = (const float*)d_in[8];
    const float* W4  = (const float*)d_in[9];
    const float* b4  = (const float*)d_in[10];
    const float* W5  = (const float*)d_in[11];
    const float* b5  = (const float*)d_in[12];
    const float* fW1 = (const float*)d_in[13];
    const float* fb1 = (const float*)d_in[14];
    const float* fW2 = (const float*)d_in[15];
    const float* fb2 = (const float*)d_in[16];
    float* out = (float*)d_out;

    char* ws = (char*)d_ws;
    size_t o = 0;
    auto alloc = [&](size_t elems) -> void* {
        void* p = (void*)(ws + o);
        o += ((elems * 4 + 255) / 256) * 256;
        return p;
    };
    float* dinv   = (float*)alloc(NN);
    float* xd     = (float*)alloc(NN);
    int*   rowptr = (int*)alloc(NN + 1);
    unsigned long long* cnt64 = (unsigned long long*)alloc(2 * (size_t)NN);
    int*   bsum   = (int*)alloc(128);
    int2*  epair  = (int2*)alloc(2 * (size_t)EE);
    unsigned* Ga16 = (unsigned*)alloc((size_t)NN * 32);   // bf16 feature rows
    unsigned* Gb16 = (unsigned*)alloc((size_t)NN * 32);
    int*   slot   = (int*)alloc(EE);
    unsigned* Wf  = (unsigned*)alloc(5 * 4096);           // pre-packed W frags

    int gE  = (EE + 255) / 256;
    int nb  = (NN + 1023) / 1024;    // 98
    int gW8 = NN / 32;               // 3125: 4 waves x 8 nodes per block

    k_wpk<<<5, 256, 0, stream>>>(W2, W3, W4, W5, fW1, Wf);
    hipMemsetAsync(cnt64, 0, NN * sizeof(unsigned long long), stream);
    k_count<<<gE, 256, 0, stream>>>(ei, ew, cnt64, slot);
    k_bsum<<<nb, 256, 0, stream>>>(cnt64, bsum);
    k_scan_out<<<nb, 256, 0, stream>>>(cnt64, bsum, x, rowptr, dinv, xd);
    k_fill<<<gE, 256, 0, stream>>>(ei, ew, slot, rowptr, epair);

    // Layer 1 (8-node/wave scalar agg + MFMA W2 tail) -> G2' bf16
    k_l1<<<gW8, 256, 0, stream>>>(xd, dinv, rowptr, epair, W1, b1, Wf + 0,
                                  (unsigned short*)Ga16);
    // Layers 2..4: fused eighth-wave gather + MFMA matvec
    k_gmv<<<gW8, 256, 0, stream>>>(Ga16, dinv, rowptr, epair, b2, Wf + 4096,
                                   (unsigned short*)Gb16);
    k_gmv<<<gW8, 256, 0, stream>>>(Gb16, dinv, rowptr, epair, b3, Wf + 8192,
                                   (unsigned short*)Ga16);
    k_gmv<<<gW8, 256, 0, stream>>>(Ga16, dinv, rowptr, epair, b4, Wf + 12288,
                                   (unsigned short*)Gb16);
    // Layer 5 + head fused
    k_ghead<<<gW8, 256, 0, stream>>>(Gb16, dinv, rowptr, epair, b5, Wf + 16384,
                                     fb1, fW2, fb2, out);
}